// Round 1
// baseline (1002.376 us; speedup 1.0000x reference)
//
#include <hip/hip_runtime.h>
#include <cstdint>
#include <cstddef>

// ---------------- constants ----------------
#define BQ 4
#define SQ 2048
#define DQ 1024
#define HQ 16
#define HDQ 64
#define FQ 4096
#define MROWS (BQ * SQ) // 8192

typedef __attribute__((ext_vector_type(8))) __bf16 bf16x8;
typedef __attribute__((ext_vector_type(8))) short s16x8;
typedef __attribute__((ext_vector_type(4))) float f32x4;

__device__ __forceinline__ unsigned short f2bf(float f) {
  unsigned int u = __builtin_bit_cast(unsigned int, f);
  u = (u + 0x7FFFu + ((u >> 16) & 1u)) >> 16;
  return (unsigned short)u;
}
__device__ __forceinline__ float bf2f(unsigned short h) {
  unsigned int u = ((unsigned int)h) << 16;
  return __builtin_bit_cast(float, u);
}

typedef const unsigned int __attribute__((address_space(1))) *as1_cu32;
typedef unsigned int __attribute__((address_space(3))) *as3_u32;
// async global->LDS, 16B per lane; LDS dest is wave-uniform base + lane*16
#define GLD16(g, l) __builtin_amdgcn_global_load_lds((as1_cu32)(const void*)(g), (as3_u32)(void*)(l), 16, 0, 0)

// ---------------- weight transpose+convert: src[R][C] f32 -> dst[C][R] bf16 ----------------
__global__ __launch_bounds__(256) void k_transpose_bf16(const float* __restrict__ src,
                                                        unsigned short* __restrict__ dst,
                                                        int R, int C) {
  __shared__ float tile[32][33];
  int tx = threadIdx.x & 31, ty = threadIdx.x >> 5; // ty 0..7
  int c0 = blockIdx.x * 32, r0 = blockIdx.y * 32;
#pragma unroll
  for (int i = 0; i < 32; i += 8)
    tile[ty + i][tx] = src[(size_t)(r0 + ty + i) * C + (c0 + tx)];
  __syncthreads();
#pragma unroll
  for (int i = 0; i < 32; i += 8)
    dst[(size_t)(c0 + ty + i) * R + (r0 + tx)] = f2bf(tile[tx][ty + i]);
}

// ---------------- RMSNorm: f32 in -> bf16 out, one block per row (D=1024) ----------------
__global__ __launch_bounds__(256) void k_rmsnorm(const float* __restrict__ x,
                                                 const float* __restrict__ g,
                                                 unsigned short* __restrict__ out) {
  int row = blockIdx.x, tid = threadIdx.x;
  const float4 v = ((const float4*)(x + (size_t)row * DQ))[tid];
  float ss = v.x * v.x + v.y * v.y + v.z * v.z + v.w * v.w;
#pragma unroll
  for (int d = 32; d >= 1; d >>= 1) ss += __shfl_xor(ss, d);
  __shared__ float ws4[4];
  if ((tid & 63) == 0) ws4[tid >> 6] = ss;
  __syncthreads();
  float tot = ws4[0] + ws4[1] + ws4[2] + ws4[3];
  float r = rsqrtf(tot * (1.0f / DQ) + 1e-6f);
  const float4 gv = ((const float4*)g)[tid];
  ushort4 o;
  o.x = f2bf(v.x * r * gv.x);
  o.y = f2bf(v.y * r * gv.y);
  o.z = f2bf(v.z * r * gv.z);
  o.w = f2bf(v.w * r * gv.w);
  ((ushort4*)(out + (size_t)row * DQ))[tid] = o;
}

// ---------------- GEMM: C[M][N] = A[M][K](bf16) x Bt[N][K](bf16)^T ----------------
// MODE 0: C bf16.  MODE 1: C f32 = acc + Res.  MODE 2: C bf16 = gelu(acc) * bf2f(C_prev)
template <int MODE>
__global__ __launch_bounds__(256) void k_gemm_bt(const unsigned short* __restrict__ A,
                                                 const unsigned short* __restrict__ Bt,
                                                 void* __restrict__ Cp,
                                                 const float* __restrict__ Res,
                                                 int M, int N, int K) {
  __shared__ __align__(16) unsigned short As[128 * 32];
  __shared__ __align__(16) unsigned short Bs[128 * 32];
  const int tid = threadIdx.x;
  const int lane = tid & 63, w = tid >> 6;
  const int m0 = blockIdx.y * 128, n0 = blockIdx.x * 128;
  const int wm = (w >> 1) * 64, wn = (w & 1) * 64;
  const int lr = lane & 15, lg = lane >> 4;
  f32x4 acc[4][4] = {};
  for (int k0 = 0; k0 < K; k0 += 32) {
#pragma unroll
    for (int i = 0; i < 2; ++i) {
      int flat = i * 256 + tid;
      int row = flat >> 2, ch = flat & 3;
      GLD16(A + (size_t)(m0 + row) * K + k0 + ch * 8, As + (size_t)(i * 256 + w * 64) * 8);
      GLD16(Bt + (size_t)(n0 + row) * K + k0 + ch * 8, Bs + (size_t)(i * 256 + w * 64) * 8);
    }
    __syncthreads();
    bf16x8 af[4], bfr[4];
#pragma unroll
    for (int mi = 0; mi < 4; ++mi)
      af[mi] = *(const bf16x8*)(As + (wm + mi * 16 + lr) * 32 + lg * 8);
#pragma unroll
    for (int ni = 0; ni < 4; ++ni)
      bfr[ni] = *(const bf16x8*)(Bs + (wn + ni * 16 + lr) * 32 + lg * 8);
#pragma unroll
    for (int mi = 0; mi < 4; ++mi)
#pragma unroll
      for (int ni = 0; ni < 4; ++ni)
        acc[mi][ni] = __builtin_amdgcn_mfma_f32_16x16x32_bf16(af[mi], bfr[ni], acc[mi][ni], 0, 0, 0);
    __syncthreads();
  }
#pragma unroll
  for (int mi = 0; mi < 4; ++mi) {
#pragma unroll
    for (int r = 0; r < 4; ++r) {
      int gr = m0 + wm + mi * 16 + lg * 4 + r;
#pragma unroll
      for (int ni = 0; ni < 4; ++ni) {
        int gc = n0 + wn + ni * 16 + lr;
        size_t idx = (size_t)gr * N + gc;
        float v = acc[mi][ni][r];
        if (MODE == 0) {
          ((unsigned short*)Cp)[idx] = f2bf(v);
        } else if (MODE == 1) {
          ((float*)Cp)[idx] = v + Res[idx];
        } else {
          float u = bf2f(((unsigned short*)Cp)[idx]);
          float t = v + 0.044715f * v * v * v;
          float gl = 0.5f * v * (1.0f + tanhf(0.7978845608028654f * t));
          ((unsigned short*)Cp)[idx] = f2bf(gl * u);
        }
      }
    }
  }
}

// ---------------- RoPE + permute [b,s,h,hd] -> [b,h,s,hd]; q scaled by 1/8 ----------------
__global__ __launch_bounds__(512) void k_rope(const unsigned short* __restrict__ qkv,
                                              const int* __restrict__ pos,
                                              unsigned short* __restrict__ qp,
                                              unsigned short* __restrict__ kp,
                                              unsigned short* __restrict__ vp) {
  int bs = blockIdx.x;             // 0..8191
  int b = bs >> 11, s = bs & 2047;
  int t = threadIdx.x;             // 0..511
  int hh = t >> 5, j = t & 31;
  float fp = (float)pos[bs];
  const unsigned short* row = qkv + (size_t)bs * 3072;
  float q1 = bf2f(row[hh * 64 + j]);
  float q2 = bf2f(row[hh * 64 + 32 + j]);
  float k1 = bf2f(row[1024 + hh * 64 + j]);
  float k2 = bf2f(row[1024 + hh * 64 + 32 + j]);
  float ts = powf(10000.0f, (float)j * (1.0f / 32.0f));
  float ang = fp / ts;
  float sn = sinf(ang), cs = cosf(ang);
  size_t o = ((size_t)(b * HQ + hh) * SQ + s) * HDQ + j;
  qp[o]      = f2bf((q1 * cs - q2 * sn) * 0.125f);
  qp[o + 32] = f2bf((q2 * cs + q1 * sn) * 0.125f);
  kp[o]      = f2bf(k1 * cs - k2 * sn);
  kp[o + 32] = f2bf(k2 * cs + k1 * sn);
  vp[o]      = row[2048 + hh * 64 + j];
  vp[o + 32] = row[2048 + hh * 64 + 32 + j];
}

// ---------------- causal flash attention: QB=64 (4 waves x 16 rows), KV tile 32 ----------------
__global__ __launch_bounds__(256) void k_flash(const unsigned short* __restrict__ qp,
                                               const unsigned short* __restrict__ kp,
                                               const unsigned short* __restrict__ vp,
                                               unsigned short* __restrict__ ctx) {
  int qb = (int)gridDim.x - 1 - (int)blockIdx.x; // heavy blocks first
  int bh = blockIdx.y;
  int b = bh >> 4, hh = bh & 15;
  __shared__ __align__(16) unsigned short Ks[32 * 64];  // [kv][hd]
  __shared__ __align__(16) unsigned short Vt[64 * 40];  // [hd][kv], stride 40 (80B, 16B-aligned rows)
  __shared__ __align__(16) unsigned short Ps[4][16 * 32];
  int tid = threadIdx.x, lane = tid & 63, w = tid >> 6;
  const int lr = lane & 15, lg = lane >> 4;
  size_t hoff = (size_t)bh * SQ * HDQ;
  const unsigned short* Q = qp + hoff;
  const unsigned short* Kg = kp + hoff;
  const unsigned short* Vg = vp + hoff;
  int qr0 = qb * 64 + w * 16;
  bf16x8 aq0 = *(const bf16x8*)(Q + (size_t)(qr0 + lr) * 64 + lg * 8);
  bf16x8 aq1 = *(const bf16x8*)(Q + (size_t)(qr0 + lr) * 64 + 32 + lg * 8);
  f32x4 accO[4] = {};
  float mrow[4] = {-1e30f, -1e30f, -1e30f, -1e30f};
  float lrow[4] = {0.f, 0.f, 0.f, 0.f};
  int nt = qb * 2 + 2;
  for (int t = 0; t < nt; ++t) {
    int kv0 = t * 32;
    { // K tile -> LDS (linear, async)
      int krow = tid >> 3, ch = tid & 7;
      GLD16(Kg + (size_t)(kv0 + krow) * 64 + ch * 8, Ks + (size_t)(w * 64) * 8);
    }
    { // V tile -> LDS transposed: lanes 0..31 share chunk, spread rows -> conflict-light
      int rr = tid & 31, cb = (tid >> 5) * 8;
      bf16x8 vv = *(const bf16x8*)(Vg + (size_t)(kv0 + rr) * 64 + cb);
      s16x8 vs = __builtin_bit_cast(s16x8, vv);
#pragma unroll
      for (int jj = 0; jj < 8; ++jj)
        Vt[(cb + jj) * 40 + rr] = (unsigned short)vs[jj];
    }
    __syncthreads();
    // S = Q K^T  (two 16-col halves, K-dim 64 = 2 mfma)
    f32x4 sacc[2] = {};
#pragma unroll
    for (int nh = 0; nh < 2; ++nh) {
      bf16x8 bk0 = *(const bf16x8*)(Ks + (nh * 16 + lr) * 64 + lg * 8);
      bf16x8 bk1 = *(const bf16x8*)(Ks + (nh * 16 + lr) * 64 + 32 + lg * 8);
      sacc[nh] = __builtin_amdgcn_mfma_f32_16x16x32_bf16(aq0, bk0, sacc[nh], 0, 0, 0);
      sacc[nh] = __builtin_amdgcn_mfma_f32_16x16x32_bf16(aq1, bk1, sacc[nh], 0, 0, 0);
    }
    // online softmax (rows owned per-lane: row = lg*4+i, 16 lanes hold the 16 cols)
    float scl[4];
#pragma unroll
    for (int i = 0; i < 4; ++i) {
      int gr = qr0 + lg * 4 + i;
      float s0 = sacc[0][i], s1 = sacc[1][i];
      if (kv0 + lr > gr) s0 = -1e30f;
      if (kv0 + 16 + lr > gr) s1 = -1e30f;
      float mt = fmaxf(s0, s1);
#pragma unroll
      for (int dd = 8; dd >= 1; dd >>= 1) mt = fmaxf(mt, __shfl_xor(mt, dd));
      float mnew = fmaxf(mrow[i], mt);
      scl[i] = __expf(mrow[i] - mnew);
      float p0 = __expf(s0 - mnew), p1 = __expf(s1 - mnew);
      float ps = p0 + p1;
#pragma unroll
      for (int dd = 8; dd >= 1; dd >>= 1) ps += __shfl_xor(ps, dd);
      lrow[i] = lrow[i] * scl[i] + ps;
      mrow[i] = mnew;
      int prow = lg * 4 + i;
      Ps[w][prow * 32 + lr] = f2bf(p0);
      Ps[w][prow * 32 + 16 + lr] = f2bf(p1);
    }
#pragma unroll
    for (int n2 = 0; n2 < 4; ++n2) {
#pragma unroll
      for (int i = 0; i < 4; ++i) accO[n2][i] *= scl[i];
    }
    bf16x8 ap = *(const bf16x8*)(&Ps[w][lr * 32 + lg * 8]);
#pragma unroll
    for (int n2 = 0; n2 < 4; ++n2) {
      bf16x8 bv = *(const bf16x8*)(Vt + (n2 * 16 + lr) * 40 + lg * 8);
      accO[n2] = __builtin_amdgcn_mfma_f32_16x16x32_bf16(ap, bv, accO[n2], 0, 0, 0);
    }
    __syncthreads();
  }
  float linv[4];
#pragma unroll
  for (int i = 0; i < 4; ++i) linv[i] = 1.0f / lrow[i];
#pragma unroll
  for (int n2 = 0; n2 < 4; ++n2) {
#pragma unroll
    for (int i = 0; i < 4; ++i) {
      int gs = qr0 + lg * 4 + i;
      int gc = n2 * 16 + lr;
      ctx[((size_t)b * SQ + gs) * DQ + hh * 64 + gc] = f2bf(accO[n2][i] * linv[i]);
    }
  }
}

// ---------------- launch ----------------
extern "C" void kernel_launch(void* const* d_in, const int* in_sizes, int n_in,
                              void* d_out, int out_size, void* d_ws, size_t ws_size,
                              hipStream_t stream) {
  (void)in_sizes; (void)n_in; (void)out_size; (void)ws_size;
  const float* x   = (const float*)d_in[0];
  const int*   pos = (const int*)d_in[1];
  // d_in[2] = mask (always causal tril; handled analytically)
  const float* wq  = (const float*)d_in[3];
  const float* wk  = (const float*)d_in[4];
  const float* wv  = (const float*)d_in[5];
  const float* wo  = (const float*)d_in[6];
  const float* wg  = (const float*)d_in[7];
  const float* wu  = (const float*)d_in[8];
  const float* wd  = (const float*)d_in[9];
  const float* n1  = (const float*)d_in[10];
  const float* n2v = (const float*)d_in[11];
  char* ws = (char*)d_ws;
  const size_t MB = 1024ull * 1024ull;
  // workspace map (192 MB total, with lifetime-based aliasing):
  unsigned short* qkvT  = (unsigned short*)(ws);            // [3072][1024] bf16, 6MB
  unsigned short* woT   = (unsigned short*)(ws + 6 * MB);   // [1024][1024] 2MB
  unsigned short* gateT = (unsigned short*)(ws + 8 * MB);   // [4096][1024] 8MB
  unsigned short* upT   = (unsigned short*)(ws + 16 * MB);  // 8MB
  unsigned short* downT = (unsigned short*)(ws + 24 * MB);  // [1024][4096] 8MB
  unsigned short* qkv   = (unsigned short*)(ws + 32 * MB);  // [8192][3072] 48MB (dead after rope)
  unsigned short* act   = qkv;                              // [8192][4096] 64MB (spans into qp region, both dead)
  unsigned short* qpb   = (unsigned short*)(ws + 80 * MB);  // [64][2048][64] 16MB
  unsigned short* kpb   = (unsigned short*)(ws + 96 * MB);  // 16MB
  unsigned short* vpb   = (unsigned short*)(ws + 112 * MB); // 16MB
  unsigned short* hbuf  = (unsigned short*)(ws + 128 * MB); // [8192][1024] 16MB (reused as ctx)
  unsigned short* ctx   = hbuf;
  float*          x2    = (float*)(ws + 144 * MB);          // [8192][1024] f32 32MB
  unsigned short* h2    = (unsigned short*)(ws + 176 * MB); // 16MB
  float*          out   = (float*)d_out;

  dim3 b256(256);
  // weights -> bf16 transposed (B^T form)
  k_transpose_bf16<<<dim3(32, 32), b256, 0, stream>>>(wq, qkvT, 1024, 1024);
  k_transpose_bf16<<<dim3(32, 32), b256, 0, stream>>>(wk, qkvT + 1024 * 1024, 1024, 1024);
  k_transpose_bf16<<<dim3(32, 32), b256, 0, stream>>>(wv, qkvT + 2 * 1024 * 1024, 1024, 1024);
  k_transpose_bf16<<<dim3(32, 32), b256, 0, stream>>>(wo, woT, 1024, 1024);
  k_transpose_bf16<<<dim3(128, 32), b256, 0, stream>>>(wg, gateT, 1024, 4096);
  k_transpose_bf16<<<dim3(128, 32), b256, 0, stream>>>(wu, upT, 1024, 4096);
  k_transpose_bf16<<<dim3(32, 128), b256, 0, stream>>>(wd, downT, 4096, 1024);
  // attention block
  k_rmsnorm<<<MROWS, b256, 0, stream>>>(x, n1, hbuf);
  k_gemm_bt<0><<<dim3(24, 64), b256, 0, stream>>>(hbuf, qkvT, qkv, nullptr, MROWS, 3072, 1024);
  k_rope<<<MROWS, dim3(512), 0, stream>>>(qkv, pos, qpb, kpb, vpb);
  k_flash<<<dim3(32, 64), b256, 0, stream>>>(qpb, kpb, vpb, ctx);
  k_gemm_bt<1><<<dim3(8, 64), b256, 0, stream>>>(ctx, woT, x2, x, MROWS, 1024, 1024);
  // FFN block
  k_rmsnorm<<<MROWS, b256, 0, stream>>>(x2, n2v, h2);
  k_gemm_bt<0><<<dim3(32, 64), b256, 0, stream>>>(h2, upT, act, nullptr, MROWS, 4096, 1024);
  k_gemm_bt<2><<<dim3(32, 64), b256, 0, stream>>>(h2, gateT, act, nullptr, MROWS, 4096, 1024);
  k_gemm_bt<1><<<dim3(8, 64), b256, 0, stream>>>(act, downT, out, x2, MROWS, 1024, 4096);
}

// Round 3
// 840.503 us; speedup vs baseline: 1.1926x; 1.1926x over previous
//
#include <hip/hip_runtime.h>
#include <cstdint>
#include <cstddef>

// ---------------- constants ----------------
#define BQ 4
#define SQ 2048
#define DQ 1024
#define HQ 16
#define HDQ 64
#define FQ 4096
#define MROWS (BQ * SQ) // 8192

typedef __attribute__((ext_vector_type(8))) __bf16 bf16x8;
typedef __attribute__((ext_vector_type(8))) unsigned short u16x8;
typedef __attribute__((ext_vector_type(4))) float f32x4;

__device__ __forceinline__ unsigned short f2bf(float f) {
  unsigned int u = __builtin_bit_cast(unsigned int, f);
  u = (u + 0x7FFFu + ((u >> 16) & 1u)) >> 16;
  return (unsigned short)u;
}
__device__ __forceinline__ float bf2f(unsigned short h) {
  unsigned int u = ((unsigned int)h) << 16;
  return __builtin_bit_cast(float, u);
}

typedef const unsigned int __attribute__((address_space(1))) *as1_cu32;
typedef unsigned int __attribute__((address_space(3))) *as3_u32;
// async global->LDS, 16B per lane; LDS dest is wave-uniform base + lane*16
#define GLD16(g, l) __builtin_amdgcn_global_load_lds((as1_cu32)(const void*)(g), (as3_u32)(void*)(l), 16, 0, 0)

// ---------------- weight transpose+convert: src[R][C] f32 -> dst[C][R] bf16 ----------------
__global__ __launch_bounds__(256) void k_transpose_bf16(const float* __restrict__ src,
                                                        unsigned short* __restrict__ dst,
                                                        int R, int C) {
  __shared__ float tile[32][33];
  int tx = threadIdx.x & 31, ty = threadIdx.x >> 5; // ty 0..7
  int c0 = blockIdx.x * 32, r0 = blockIdx.y * 32;
#pragma unroll
  for (int i = 0; i < 32; i += 8)
    tile[ty + i][tx] = src[(size_t)(r0 + ty + i) * C + (c0 + tx)];
  __syncthreads();
#pragma unroll
  for (int i = 0; i < 32; i += 8)
    dst[(size_t)(c0 + ty + i) * R + (r0 + tx)] = f2bf(tile[tx][ty + i]);
}

// ---------------- RMSNorm: f32 in -> bf16 out, one block per row (D=1024) ----------------
__global__ __launch_bounds__(256) void k_rmsnorm(const float* __restrict__ x,
                                                 const float* __restrict__ g,
                                                 unsigned short* __restrict__ out) {
  int row = blockIdx.x, tid = threadIdx.x;
  const float4 v = ((const float4*)(x + (size_t)row * DQ))[tid];
  float ss = v.x * v.x + v.y * v.y + v.z * v.z + v.w * v.w;
#pragma unroll
  for (int d = 32; d >= 1; d >>= 1) ss += __shfl_xor(ss, d);
  __shared__ float ws4[4];
  if ((tid & 63) == 0) ws4[tid >> 6] = ss;
  __syncthreads();
  float tot = ws4[0] + ws4[1] + ws4[2] + ws4[3];
  float r = rsqrtf(tot * (1.0f / DQ) + 1e-6f);
  const float4 gv = ((const float4*)g)[tid];
  ushort4 o;
  o.x = f2bf(v.x * r * gv.x);
  o.y = f2bf(v.y * r * gv.y);
  o.z = f2bf(v.z * r * gv.z);
  o.w = f2bf(v.w * r * gv.w);
  ((ushort4*)(out + (size_t)row * DQ))[tid] = o;
}

// ---------------- GEMM: C[M][N] = A[M][K](bf16) x Bt[N][K](bf16)^T ----------------
// MODE 0: C bf16.  MODE 1: C f32 = acc + Res.  MODE 2: C bf16 = gelu(acc) * bf2f(C_prev)
template <int MODE>
__global__ __launch_bounds__(256) void k_gemm_bt(const unsigned short* __restrict__ A,
                                                 const unsigned short* __restrict__ Bt,
                                                 void* __restrict__ Cp,
                                                 const float* __restrict__ Res,
                                                 int M, int N, int K) {
  __shared__ __align__(16) unsigned short As[128 * 32];
  __shared__ __align__(16) unsigned short Bs[128 * 32];
  const int tid = threadIdx.x;
  const int lane = tid & 63, w = tid >> 6;
  const int m0 = blockIdx.y * 128, n0 = blockIdx.x * 128;
  const int wm = (w >> 1) * 64, wn = (w & 1) * 64;
  const int lr = lane & 15, lg = lane >> 4;
  f32x4 acc[4][4] = {};
  for (int k0 = 0; k0 < K; k0 += 32) {
#pragma unroll
    for (int i = 0; i < 2; ++i) {
      int flat = i * 256 + tid;
      int row = flat >> 2, ch = flat & 3;
      GLD16(A + (size_t)(m0 + row) * K + k0 + ch * 8, As + (size_t)(i * 256 + w * 64) * 8);
      GLD16(Bt + (size_t)(n0 + row) * K + k0 + ch * 8, Bs + (size_t)(i * 256 + w * 64) * 8);
    }
    __syncthreads();
    bf16x8 af[4], bfr[4];
#pragma unroll
    for (int mi = 0; mi < 4; ++mi)
      af[mi] = *(const bf16x8*)(As + (wm + mi * 16 + lr) * 32 + lg * 8);
#pragma unroll
    for (int ni = 0; ni < 4; ++ni)
      bfr[ni] = *(const bf16x8*)(Bs + (wn + ni * 16 + lr) * 32 + lg * 8);
#pragma unroll
    for (int mi = 0; mi < 4; ++mi)
#pragma unroll
      for (int ni = 0; ni < 4; ++ni)
        acc[mi][ni] = __builtin_amdgcn_mfma_f32_16x16x32_bf16(af[mi], bfr[ni], acc[mi][ni], 0, 0, 0);
    __syncthreads();
  }
#pragma unroll
  for (int mi = 0; mi < 4; ++mi) {
#pragma unroll
    for (int r = 0; r < 4; ++r) {
      int gr = m0 + wm + mi * 16 + lg * 4 + r;
#pragma unroll
      for (int ni = 0; ni < 4; ++ni) {
        int gc = n0 + wn + ni * 16 + lr;
        size_t idx = (size_t)gr * N + gc;
        float v = acc[mi][ni][r];
        if (MODE == 0) {
          ((unsigned short*)Cp)[idx] = f2bf(v);
        } else if (MODE == 1) {
          ((float*)Cp)[idx] = v + Res[idx];
        } else {
          float u = bf2f(((unsigned short*)Cp)[idx]);
          float t = v + 0.044715f * v * v * v;
          float gl = 0.5f * v * (1.0f + tanhf(0.7978845608028654f * t));
          ((unsigned short*)Cp)[idx] = f2bf(gl * u);
        }
      }
    }
  }
}

// ---------------- RoPE: qkv[b,s,3*D] -> qp/kp [bh][s][64], V -> vpT [bh][hd][s] ----------------
// q scaled by (1/sqrt(64)) * log2(e) so flash softmax can use exp2 directly.
// Block = (s-tile of 64) x (one bh). 256 threads: 4 threads per s-row, 8 rope-pairs each.
__global__ __launch_bounds__(256) void k_rope(const unsigned short* __restrict__ qkv,
                                              const int* __restrict__ pos,
                                              unsigned short* __restrict__ qp,
                                              unsigned short* __restrict__ kp,
                                              unsigned short* __restrict__ vpT) {
  __shared__ unsigned short T[64 * 67]; // [s_local][hd], stride 67 to spread banks
  const float NEG_L2TS = -0.4152410118609203f; // -log2(10000)/32
  const float QSCALE = 0.125f * 1.4426950408889634f;
  int bh = blockIdx.y, b = bh >> 4, hh = bh & 15;
  int s0 = blockIdx.x * 64;
  int tid = threadIdx.x;
  int row = tid >> 2, q4 = tid & 3, j0 = q4 * 8;
  int gs = s0 + row;
  const unsigned short* base = qkv + ((size_t)(b * SQ + gs)) * 3072 + hh * 64;
  u16x8 q1 = *(const u16x8*)(base + j0);
  u16x8 q2 = *(const u16x8*)(base + 32 + j0);
  u16x8 k1 = *(const u16x8*)(base + 1024 + j0);
  u16x8 k2 = *(const u16x8*)(base + 1024 + 32 + j0);
  u16x8 v1 = *(const u16x8*)(base + 2048 + j0);
  u16x8 v2 = *(const u16x8*)(base + 2048 + 32 + j0);
  float fp = (float)pos[b * SQ + gs];
  u16x8 oq1, oq2, ok1, ok2;
#pragma unroll
  for (int jj = 0; jj < 8; ++jj) {
    float ang = fp * exp2f((float)(j0 + jj) * NEG_L2TS);
    float sn, cs;
    __sincosf(ang, &sn, &cs);
    float q1f = bf2f(q1[jj]), q2f = bf2f(q2[jj]);
    float k1f = bf2f(k1[jj]), k2f = bf2f(k2[jj]);
    oq1[jj] = f2bf((q1f * cs - q2f * sn) * QSCALE);
    oq2[jj] = f2bf((q2f * cs + q1f * sn) * QSCALE);
    ok1[jj] = f2bf(k1f * cs - k2f * sn);
    ok2[jj] = f2bf(k2f * cs + k1f * sn);
    T[row * 67 + j0 + jj] = v1[jj];
    T[row * 67 + 32 + j0 + jj] = v2[jj];
  }
  size_t o = ((size_t)bh * SQ + gs) * 64;
  *(u16x8*)(qp + o + j0) = oq1;
  *(u16x8*)(qp + o + 32 + j0) = oq2;
  *(u16x8*)(kp + o + j0) = ok1;
  *(u16x8*)(kp + o + 32 + j0) = ok2;
  __syncthreads();
  // transposed V out: [bh][hd][s]
  int hd = tid >> 2;
#pragma unroll
  for (int c2 = 0; c2 < 2; ++c2) {
    int sb = q4 * 16 + c2 * 8;
    u16x8 ov;
#pragma unroll
    for (int ii = 0; ii < 8; ++ii) ov[ii] = T[(sb + ii) * 67 + hd];
    *(u16x8*)(vpT + ((size_t)bh * 64 + hd) * SQ + s0 + sb) = ov;
  }
}

// ---------------- causal flash attention: QB=64 (4 waves x 16 rows), KV tile 64 ----------------
// K tile [kv][64], V^T tile [hd][kv] both staged via swizzled-source global_load_lds
// (LDS linear, chunk XOR row&7 on source AND on ds_read -> conflict-free b128 reads).
__global__ __launch_bounds__(256) void k_flash(const unsigned short* __restrict__ qp,
                                               const unsigned short* __restrict__ kp,
                                               const unsigned short* __restrict__ vpT,
                                               unsigned short* __restrict__ ctx) {
  __shared__ __align__(16) unsigned short Ks[2][64 * 64];
  __shared__ __align__(16) unsigned short Vs[2][64 * 64];
  __shared__ __align__(16) unsigned short Ps[4][16 * 64];
  int qb = 31 - (int)blockIdx.x; // heavy blocks first
  int bh = blockIdx.y, b = bh >> 4, hh = bh & 15;
  int tid = threadIdx.x, lane = tid & 63, w = tid >> 6;
  const int lr = lane & 15, lg = lane >> 4;
  const int key = lr & 7;
  size_t hoff = (size_t)bh * SQ * 64;
  const unsigned short* Q = qp + hoff;
  const unsigned short* Kg = kp + hoff;
  const unsigned short* Vh = vpT + hoff; // [64 hd][2048 s]
  int qr0 = qb * 64 + w * 16;
  bf16x8 aq0 = *(const bf16x8*)(Q + (size_t)(qr0 + lr) * 64 + lg * 8);
  bf16x8 aq1 = *(const bf16x8*)(Q + (size_t)(qr0 + lr) * 64 + 32 + lg * 8);
  f32x4 accO[4] = {};
  float mrow[4] = {-1e30f, -1e30f, -1e30f, -1e30f};
  float lrow[4] = {0.f, 0.f, 0.f, 0.f};
  int nt = qb + 1;

#define STAGE(d, t)                                                              \
  {                                                                              \
    int kv0s = (t) * 64;                                                         \
    _Pragma("unroll") for (int i = 0; i < 2; ++i) {                              \
      int flat = i * 256 + tid;                                                  \
      int srow = flat >> 3;                                                      \
      int ch = (flat & 7) ^ (srow & 7);                                          \
      GLD16(Kg + (size_t)(kv0s + srow) * 64 + ch * 8, &Ks[d][(i * 256 + w * 64) * 8]); \
      GLD16(Vh + (size_t)srow * SQ + kv0s + ch * 8, &Vs[d][(i * 256 + w * 64) * 8]);   \
    }                                                                            \
  }

  STAGE(0, 0);
  __syncthreads();
  for (int t = 0; t < nt; ++t) {
    int kv0 = t * 64;
    if (t + 1 < nt) STAGE((t + 1) & 1, t + 1); // async prefetch; drained by loop-end barrier
    const unsigned short* Kc = Ks[t & 1];
    const unsigned short* Vc = Vs[t & 1];
    f32x4 sacc[4] = {};
#pragma unroll
    for (int nh = 0; nh < 4; ++nh) {
      const unsigned short* kr = Kc + (nh * 16 + lr) * 64;
      bf16x8 b0 = *(const bf16x8*)(kr + (lg ^ key) * 8);
      bf16x8 b1 = *(const bf16x8*)(kr + ((lg + 4) ^ key) * 8);
      sacc[nh] = __builtin_amdgcn_mfma_f32_16x16x32_bf16(aq0, b0, sacc[nh], 0, 0, 0);
      sacc[nh] = __builtin_amdgcn_mfma_f32_16x16x32_bf16(aq1, b1, sacc[nh], 0, 0, 0);
    }
    bool diag = (t == qb);
    float scl[4];
#pragma unroll
    for (int i = 0; i < 4; ++i) {
      float s0 = sacc[0][i], s1 = sacc[1][i], s2 = sacc[2][i], s3 = sacc[3][i];
      if (diag) {
        int gr = qr0 + lg * 4 + i;
        int c = kv0 + lr;
        if (c > gr) s0 = -1e30f;
        if (c + 16 > gr) s1 = -1e30f;
        if (c + 32 > gr) s2 = -1e30f;
        if (c + 48 > gr) s3 = -1e30f;
      }
      float mt = fmaxf(fmaxf(s0, s1), fmaxf(s2, s3));
      mt = fmaxf(mt, __shfl_xor(mt, 1));
      mt = fmaxf(mt, __shfl_xor(mt, 2));
      mt = fmaxf(mt, __shfl_xor(mt, 4));
      mt = fmaxf(mt, __shfl_xor(mt, 8));
      float mnew = fmaxf(mrow[i], mt);
      scl[i] = exp2f(mrow[i] - mnew);
      mrow[i] = mnew;
      float p0 = exp2f(s0 - mnew), p1 = exp2f(s1 - mnew);
      float p2 = exp2f(s2 - mnew), p3 = exp2f(s3 - mnew);
      lrow[i] = lrow[i] * scl[i] + (p0 + p1 + p2 + p3); // per-lane partial; reduced once at end
      int prow = lg * 4 + i;
      unsigned short* Pr = &Ps[w][prow * 64];
      int pk = prow & 7;
      int sub = lr >> 3, off = lr & 7;
      Pr[((0 + sub) ^ pk) * 8 + off] = f2bf(p0);
      Pr[((2 + sub) ^ pk) * 8 + off] = f2bf(p1);
      Pr[((4 + sub) ^ pk) * 8 + off] = f2bf(p2);
      Pr[((6 + sub) ^ pk) * 8 + off] = f2bf(p3);
    }
#pragma unroll
    for (int n2 = 0; n2 < 4; ++n2)
#pragma unroll
      for (int i = 0; i < 4; ++i) accO[n2][i] *= scl[i];
    bf16x8 ap0 = *(const bf16x8*)(&Ps[w][lr * 64] + (lg ^ key) * 8);
    bf16x8 ap1 = *(const bf16x8*)(&Ps[w][lr * 64] + ((lg + 4) ^ key) * 8);
#pragma unroll
    for (int n2 = 0; n2 < 4; ++n2) {
      const unsigned short* vr = Vc + (n2 * 16 + lr) * 64;
      bf16x8 bv0 = *(const bf16x8*)(vr + (lg ^ key) * 8);
      bf16x8 bv1 = *(const bf16x8*)(vr + ((lg + 4) ^ key) * 8);
      accO[n2] = __builtin_amdgcn_mfma_f32_16x16x32_bf16(ap0, bv0, accO[n2], 0, 0, 0);
      accO[n2] = __builtin_amdgcn_mfma_f32_16x16x32_bf16(ap1, bv1, accO[n2], 0, 0, 0);
    }
    __syncthreads(); // drains prefetch vmcnt + protects dbuf
  }
#pragma unroll
  for (int i = 0; i < 4; ++i) {
    float l = lrow[i];
    l += __shfl_xor(l, 1);
    l += __shfl_xor(l, 2);
    l += __shfl_xor(l, 4);
    l += __shfl_xor(l, 8);
    lrow[i] = 1.0f / l;
  }
#pragma unroll
  for (int n2 = 0; n2 < 4; ++n2)
#pragma unroll
    for (int i = 0; i < 4; ++i) {
      int gs = qr0 + lg * 4 + i;
      ctx[((size_t)b * SQ + gs) * DQ + hh * 64 + n2 * 16 + lr] = f2bf(accO[n2][i] * lrow[i]);
    }
#undef STAGE
}

// ---------------- launch ----------------
extern "C" void kernel_launch(void* const* d_in, const int* in_sizes, int n_in,
                              void* d_out, int out_size, void* d_ws, size_t ws_size,
                              hipStream_t stream) {
  (void)in_sizes; (void)n_in; (void)out_size; (void)ws_size;
  const float* x   = (const float*)d_in[0];
  const int*   pos = (const int*)d_in[1];
  // d_in[2] = mask (always causal tril; handled analytically)
  const float* wq  = (const float*)d_in[3];
  const float* wk  = (const float*)d_in[4];
  const float* wv  = (const float*)d_in[5];
  const float* wo  = (const float*)d_in[6];
  const float* wg  = (const float*)d_in[7];
  const float* wu  = (const float*)d_in[8];
  const float* wd  = (const float*)d_in[9];
  const float* n1  = (const float*)d_in[10];
  const float* n2v = (const float*)d_in[11];
  char* ws = (char*)d_ws;
  const size_t MB = 1024ull * 1024ull;
  // workspace map (192 MB total, with lifetime-based aliasing):
  unsigned short* qkvT  = (unsigned short*)(ws);            // [3072][1024] bf16, 6MB
  unsigned short* woT   = (unsigned short*)(ws + 6 * MB);   // [1024][1024] 2MB
  unsigned short* gateT = (unsigned short*)(ws + 8 * MB);   // [4096][1024] 8MB
  unsigned short* upT   = (unsigned short*)(ws + 16 * MB);  // 8MB
  unsigned short* downT = (unsigned short*)(ws + 24 * MB);  // [1024][4096] 8MB
  unsigned short* qkv   = (unsigned short*)(ws + 32 * MB);  // [8192][3072] 48MB (dead after rope)
  unsigned short* act   = qkv;                              // [8192][4096] 64MB (qkv+qp dead by then)
  unsigned short* qpb   = (unsigned short*)(ws + 80 * MB);  // [64][2048][64] 16MB
  unsigned short* kpb   = (unsigned short*)(ws + 96 * MB);  // 16MB
  unsigned short* vpT   = (unsigned short*)(ws + 112 * MB); // [64][64][2048] 16MB
  unsigned short* hbuf  = (unsigned short*)(ws + 128 * MB); // [8192][1024] 16MB (reused as ctx)
  unsigned short* ctx   = hbuf;
  float*          x2    = (float*)(ws + 144 * MB);          // [8192][1024] f32 32MB
  unsigned short* h2    = (unsigned short*)(ws + 176 * MB); // 16MB
  float*          out   = (float*)d_out;

  dim3 b256(256);
  // weights -> bf16 transposed (B^T form)
  k_transpose_bf16<<<dim3(32, 32), b256, 0, stream>>>(wq, qkvT, 1024, 1024);
  k_transpose_bf16<<<dim3(32, 32), b256, 0, stream>>>(wk, qkvT + 1024 * 1024, 1024, 1024);
  k_transpose_bf16<<<dim3(32, 32), b256, 0, stream>>>(wv, qkvT + 2 * 1024 * 1024, 1024, 1024);
  k_transpose_bf16<<<dim3(32, 32), b256, 0, stream>>>(wo, woT, 1024, 1024);
  k_transpose_bf16<<<dim3(128, 32), b256, 0, stream>>>(wg, gateT, 1024, 4096);
  k_transpose_bf16<<<dim3(128, 32), b256, 0, stream>>>(wu, upT, 1024, 4096);
  k_transpose_bf16<<<dim3(32, 128), b256, 0, stream>>>(wd, downT, 4096, 1024);
  // attention block
  k_rmsnorm<<<MROWS, b256, 0, stream>>>(x, n1, hbuf);
  k_gemm_bt<0><<<dim3(24, 64), b256, 0, stream>>>(hbuf, qkvT, qkv, nullptr, MROWS, 3072, 1024);
  k_rope<<<dim3(32, 64), b256, 0, stream>>>(qkv, pos, qpb, kpb, vpT);
  k_flash<<<dim3(32, 64), b256, 0, stream>>>(qpb, kpb, vpT, ctx);
  k_gemm_bt<1><<<dim3(8, 64), b256, 0, stream>>>(ctx, woT, x2, x, MROWS, 1024, 1024);
  // FFN block
  k_rmsnorm<<<MROWS, b256, 0, stream>>>(x2, n2v, h2);
  k_gemm_bt<0><<<dim3(32, 64), b256, 0, stream>>>(h2, upT, act, nullptr, MROWS, 4096, 1024);
  k_gemm_bt<2><<<dim3(32, 64), b256, 0, stream>>>(h2, gateT, act, nullptr, MROWS, 4096, 1024);
  k_gemm_bt<1><<<dim3(8, 64), b256, 0, stream>>>(act, downT, out, x2, MROWS, 1024, 4096);
}

// Round 4
// 830.408 us; speedup vs baseline: 1.2071x; 1.0122x over previous
//
#include <hip/hip_runtime.h>
#include <cstdint>
#include <cstddef>

// ---------------- constants ----------------
#define BQ 4
#define SQ 2048
#define DQ 1024
#define HQ 16
#define HDQ 64
#define FQ 4096
#define MROWS (BQ * SQ) // 8192

typedef __attribute__((ext_vector_type(8))) __bf16 bf16x8;
typedef __attribute__((ext_vector_type(8))) unsigned short u16x8;
typedef __attribute__((ext_vector_type(4))) float f32x4;

__device__ __forceinline__ unsigned short f2bf(float f) {
  unsigned int u = __builtin_bit_cast(unsigned int, f);
  u = (u + 0x7FFFu + ((u >> 16) & 1u)) >> 16;
  return (unsigned short)u;
}
__device__ __forceinline__ float bf2f(unsigned short h) {
  unsigned int u = ((unsigned int)h) << 16;
  return __builtin_bit_cast(float, u);
}

typedef const unsigned int __attribute__((address_space(1))) *as1_cu32;
typedef unsigned int __attribute__((address_space(3))) *as3_u32;
// async global->LDS, 16B per lane; LDS dest is wave-uniform base + lane*16
#define GLD16(g, l) __builtin_amdgcn_global_load_lds((as1_cu32)(const void*)(g), (as3_u32)(void*)(l), 16, 0, 0)

// ---------------- weight transpose+convert: src[R][C] f32 -> dst[C][R] bf16 ----------------
__global__ __launch_bounds__(256) void k_transpose_bf16(const float* __restrict__ src,
                                                        unsigned short* __restrict__ dst,
                                                        int R, int C) {
  __shared__ float tile[32][33];
  int tx = threadIdx.x & 31, ty = threadIdx.x >> 5; // ty 0..7
  int c0 = blockIdx.x * 32, r0 = blockIdx.y * 32;
#pragma unroll
  for (int i = 0; i < 32; i += 8)
    tile[ty + i][tx] = src[(size_t)(r0 + ty + i) * C + (c0 + tx)];
  __syncthreads();
#pragma unroll
  for (int i = 0; i < 32; i += 8)
    dst[(size_t)(c0 + ty + i) * R + (r0 + tx)] = f2bf(tile[tx][ty + i]);
}

// ---------------- RMSNorm: f32 in -> bf16 out, one block per row (D=1024) ----------------
__global__ __launch_bounds__(256) void k_rmsnorm(const float* __restrict__ x,
                                                 const float* __restrict__ g,
                                                 unsigned short* __restrict__ out) {
  int row = blockIdx.x, tid = threadIdx.x;
  const float4 v = ((const float4*)(x + (size_t)row * DQ))[tid];
  float ss = v.x * v.x + v.y * v.y + v.z * v.z + v.w * v.w;
#pragma unroll
  for (int d = 32; d >= 1; d >>= 1) ss += __shfl_xor(ss, d);
  __shared__ float ws4[4];
  if ((tid & 63) == 0) ws4[tid >> 6] = ss;
  __syncthreads();
  float tot = ws4[0] + ws4[1] + ws4[2] + ws4[3];
  float r = rsqrtf(tot * (1.0f / DQ) + 1e-6f);
  const float4 gv = ((const float4*)g)[tid];
  ushort4 o;
  o.x = f2bf(v.x * r * gv.x);
  o.y = f2bf(v.y * r * gv.y);
  o.z = f2bf(v.z * r * gv.z);
  o.w = f2bf(v.w * r * gv.w);
  ((ushort4*)(out + (size_t)row * DQ))[tid] = o;
}

// ---------------- 128x128 GEMM (m97 structure): kept for N=1024 outputs ----------------
// MODE 0: C bf16.  MODE 1: C f32 = acc + Res.  MODE 2: C bf16 = gelu(acc) * bf2f(C_prev)
template <int MODE>
__global__ __launch_bounds__(256) void k_gemm_bt(const unsigned short* __restrict__ A,
                                                 const unsigned short* __restrict__ Bt,
                                                 void* __restrict__ Cp,
                                                 const float* __restrict__ Res,
                                                 int M, int N, int K) {
  __shared__ __align__(16) unsigned short As[128 * 32];
  __shared__ __align__(16) unsigned short Bs[128 * 32];
  const int tid = threadIdx.x;
  const int lane = tid & 63, w = tid >> 6;
  const int m0 = blockIdx.y * 128, n0 = blockIdx.x * 128;
  const int wm = (w >> 1) * 64, wn = (w & 1) * 64;
  const int lr = lane & 15, lg = lane >> 4;
  f32x4 acc[4][4] = {};
  for (int k0 = 0; k0 < K; k0 += 32) {
#pragma unroll
    for (int i = 0; i < 2; ++i) {
      int flat = i * 256 + tid;
      int row = flat >> 2, ch = flat & 3;
      GLD16(A + (size_t)(m0 + row) * K + k0 + ch * 8, As + (size_t)(i * 256 + w * 64) * 8);
      GLD16(Bt + (size_t)(n0 + row) * K + k0 + ch * 8, Bs + (size_t)(i * 256 + w * 64) * 8);
    }
    __syncthreads();
    bf16x8 af[4], bfr[4];
#pragma unroll
    for (int mi = 0; mi < 4; ++mi)
      af[mi] = *(const bf16x8*)(As + (wm + mi * 16 + lr) * 32 + lg * 8);
#pragma unroll
    for (int ni = 0; ni < 4; ++ni)
      bfr[ni] = *(const bf16x8*)(Bs + (wn + ni * 16 + lr) * 32 + lg * 8);
#pragma unroll
    for (int mi = 0; mi < 4; ++mi)
#pragma unroll
      for (int ni = 0; ni < 4; ++ni)
        acc[mi][ni] = __builtin_amdgcn_mfma_f32_16x16x32_bf16(af[mi], bfr[ni], acc[mi][ni], 0, 0, 0);
    __syncthreads();
  }
#pragma unroll
  for (int mi = 0; mi < 4; ++mi) {
#pragma unroll
    for (int r = 0; r < 4; ++r) {
      int gr = m0 + wm + mi * 16 + lg * 4 + r;
#pragma unroll
      for (int ni = 0; ni < 4; ++ni) {
        int gc = n0 + wn + ni * 16 + lr;
        size_t idx = (size_t)gr * N + gc;
        float v = acc[mi][ni][r];
        if (MODE == 0) {
          ((unsigned short*)Cp)[idx] = f2bf(v);
        } else if (MODE == 1) {
          ((float*)Cp)[idx] = v + Res[idx];
        } else {
          float u = bf2f(((unsigned short*)Cp)[idx]);
          float t = v + 0.044715f * v * v * v;
          float gl = 0.5f * v * (1.0f + tanhf(0.7978845608028654f * t));
          ((unsigned short*)Cp)[idx] = f2bf(gl * u);
        }
      }
    }
  }
}

// ---------------- 256x256 8-phase GEMM (T1+T2+T3+T4+T5), BK=64, 8 waves ----------------
// LDS 128KB: A/B x 2 halves(128 rows) x 2 dbuf, XOR-swizzled content (slot(r,c) holds
// global chunk c^(r&7)); staged via pre-swizzled global source (linear gload_lds dest).
// Per K-tile: 4 phases, each {ds_read subtile + 1 half-tile stage -> barrier ->
// setprio(1) 16xMFMA setprio(0) -> barrier}; counted vmcnt(4) once per tile at P4.
// Stage schedule (lifetimes verified): P1:A0(kt+1) P2:A1(kt+1) P3:B0(kt+2) P4:B1(kt+2).
template <int MODE>
__global__ __launch_bounds__(512, 2) void k_gemm256(const unsigned short* __restrict__ A,
                                                    const unsigned short* __restrict__ Bt,
                                                    void* __restrict__ Cp,
                                                    int M, int N, int K) {
  __shared__ __align__(16) unsigned short Ab[2][2][128 * 64];
  __shared__ __align__(16) unsigned short Bb[2][2][128 * 64];
  const int tid = threadIdx.x, lane = tid & 63, w = tid >> 6;
  const int nwg = (int)gridDim.x;
  const int nx = N >> 8;
  const int cpx = nwg >> 3; // nwg % 8 == 0 for all our launches
  const int bid = (int)blockIdx.x;
  const int swz = (bid & 7) * cpx + (bid >> 3); // bijective XCD swizzle
  const int bx = swz % nx, by = swz / nx;
  const int m0 = by * 256, n0 = bx * 256;
  const int wr = (w >> 2) * 128, wc = (w & 3) * 64;
  const int lr = lane & 15, lg = lane >> 4;
  const int NT = K >> 6;
  // staging geometry: thread handles units tid and tid+512 of a 128x64 half-tile
  const int r0 = tid >> 3;                    // rows r0 and r0+64
  const int c0sw = (tid & 7) ^ (r0 & 7);      // same swizzled chunk for both rows
  f32x4 acc[8][4] = {};

#define BAR() asm volatile("s_barrier" ::: "memory")

#define STG(isB, hh_, t_)                                                         \
  do {                                                                            \
    int tpar = (t_) & 1;                                                          \
    int t2 = (t_) > NT - 1 ? NT - 1 : (t_);                                       \
    const unsigned short* gb = (isB) ? Bt : A;                                    \
    int rb = ((isB) ? n0 : m0) + (hh_) * 128;                                     \
    unsigned short* lb =                                                          \
        ((isB) ? &Bb[tpar][hh_][0] : &Ab[tpar][hh_][0]) + (size_t)(w * 64) * 8;   \
    const unsigned short* g0 = gb + (size_t)(rb + r0) * K + t2 * 64 + c0sw * 8;   \
    GLD16(g0, lb);                                                                \
    GLD16(g0 + (size_t)64 * K, lb + 512 * 8);                                     \
  } while (0)

#define RD_A(dst, MH, par)                                                        \
  _Pragma("unroll") for (int mi2 = 0; mi2 < 4; ++mi2) {                           \
    int rr = (wr + ((MH)*4 + mi2) * 16 + lr) & 127;                               \
    int hh = wr >> 7;                                                             \
    _Pragma("unroll") for (int ks = 0; ks < 2; ++ks)                              \
        dst[mi2][ks] =                                                            \
        *(const bf16x8*)&Ab[par][hh][rr * 64 + (((ks * 4 + lg) ^ (rr & 7)) * 8)]; \
  }

#define RD_B(dst, NH, par)                                                        \
  _Pragma("unroll") for (int ni2 = 0; ni2 < 2; ++ni2) {                           \
    int c256 = wc + ((NH)*2 + ni2) * 16 + lr;                                     \
    int hh = c256 >> 7, rr = c256 & 127;                                          \
    _Pragma("unroll") for (int ks = 0; ks < 2; ++ks)                              \
        dst[ni2][ks] =                                                            \
        *(const bf16x8*)&Bb[par][hh][rr * 64 + (((ks * 4 + lg) ^ (rr & 7)) * 8)]; \
  }

#define MM(MH, NH, aqv, bqv)                                                      \
  _Pragma("unroll") for (int mi2 = 0; mi2 < 4; ++mi2)                             \
  _Pragma("unroll") for (int ni2 = 0; ni2 < 2; ++ni2)                             \
  _Pragma("unroll") for (int ks = 0; ks < 2; ++ks)                                \
      acc[(MH)*4 + mi2][(NH)*2 + ni2] = __builtin_amdgcn_mfma_f32_16x16x32_bf16(  \
          aqv[mi2][ks], bqv[ni2][ks], acc[(MH)*4 + mi2][(NH)*2 + ni2], 0, 0, 0);

  // prologue: A0(0) A1(0) B0(0) B1(0) B0(1) B1(1); wait first 8 loads (tile 0) landed
  STG(0, 0, 0);
  STG(0, 1, 0);
  STG(1, 0, 0);
  STG(1, 1, 0);
  STG(1, 0, 1);
  STG(1, 1, 1);
  asm volatile("s_waitcnt vmcnt(4)" ::: "memory");
  BAR();

  for (int kt = 0; kt < NT; ++kt) {
    const int p = kt & 1;
    bf16x8 aq[4][2], bq0[2][2], bq1[2][2];
    // P1: Q(0,0)
    RD_A(aq, 0, p);
    RD_B(bq0, 0, p);
    STG(0, 0, kt + 1);
    BAR();
    __builtin_amdgcn_s_setprio(1);
    MM(0, 0, aq, bq0);
    __builtin_amdgcn_s_setprio(0);
    BAR();
    // P2: Q(0,1)
    RD_B(bq1, 1, p);
    STG(0, 1, kt + 1);
    BAR();
    __builtin_amdgcn_s_setprio(1);
    MM(0, 1, aq, bq1);
    __builtin_amdgcn_s_setprio(0);
    BAR();
    // P3: Q(1,1)
    RD_A(aq, 1, p);
    STG(1, 0, kt + 2);
    BAR();
    __builtin_amdgcn_s_setprio(1);
    MM(1, 1, aq, bq1);
    __builtin_amdgcn_s_setprio(0);
    BAR();
    // P4: Q(1,0)
    STG(1, 1, kt + 2);
    asm volatile("s_waitcnt vmcnt(4)" ::: "memory");
    BAR();
    __builtin_amdgcn_s_setprio(1);
    MM(1, 0, aq, bq0);
    __builtin_amdgcn_s_setprio(0);
    BAR();
  }
  asm volatile("s_waitcnt vmcnt(0)" ::: "memory"); // drain clamped tail stages
#pragma unroll
  for (int mi = 0; mi < 8; ++mi) {
#pragma unroll
    for (int r = 0; r < 4; ++r) {
      int gr = m0 + wr + mi * 16 + lg * 4 + r;
#pragma unroll
      for (int ni = 0; ni < 4; ++ni) {
        int gc = n0 + wc + ni * 16 + lr;
        size_t idx = (size_t)gr * N + gc;
        float v = acc[mi][ni][r];
        if (MODE == 0) {
          ((unsigned short*)Cp)[idx] = f2bf(v);
        } else {
          float u = bf2f(((unsigned short*)Cp)[idx]);
          float t = v + 0.044715f * v * v * v;
          float gl = 0.5f * v * (1.0f + tanhf(0.7978845608028654f * t));
          ((unsigned short*)Cp)[idx] = f2bf(gl * u);
        }
      }
    }
  }
#undef BAR
#undef STG
#undef RD_A
#undef RD_B
#undef MM
}

// ---------------- RoPE: qkv[b,s,3*D] -> qp/kp [bh][s][64], V -> vpT [bh][hd][s] ----------------
// q scaled by (1/sqrt(64)) * log2(e) so flash softmax can use exp2 directly.
__global__ __launch_bounds__(256) void k_rope(const unsigned short* __restrict__ qkv,
                                              const int* __restrict__ pos,
                                              unsigned short* __restrict__ qp,
                                              unsigned short* __restrict__ kp,
                                              unsigned short* __restrict__ vpT) {
  __shared__ unsigned short T[64 * 67]; // [s_local][hd], stride 67 to spread banks
  const float NEG_L2TS = -0.4152410118609203f; // -log2(10000)/32
  const float QSCALE = 0.125f * 1.4426950408889634f;
  int bh = blockIdx.y, b = bh >> 4, hh = bh & 15;
  int s0 = blockIdx.x * 64;
  int tid = threadIdx.x;
  int row = tid >> 2, q4 = tid & 3, j0 = q4 * 8;
  int gs = s0 + row;
  const unsigned short* base = qkv + ((size_t)(b * SQ + gs)) * 3072 + hh * 64;
  u16x8 q1 = *(const u16x8*)(base + j0);
  u16x8 q2 = *(const u16x8*)(base + 32 + j0);
  u16x8 k1 = *(const u16x8*)(base + 1024 + j0);
  u16x8 k2 = *(const u16x8*)(base + 1024 + 32 + j0);
  u16x8 v1 = *(const u16x8*)(base + 2048 + j0);
  u16x8 v2 = *(const u16x8*)(base + 2048 + 32 + j0);
  float fp = (float)pos[b * SQ + gs];
  u16x8 oq1, oq2, ok1, ok2;
#pragma unroll
  for (int jj = 0; jj < 8; ++jj) {
    float ang = fp * exp2f((float)(j0 + jj) * NEG_L2TS);
    float sn, cs;
    __sincosf(ang, &sn, &cs);
    float q1f = bf2f(q1[jj]), q2f = bf2f(q2[jj]);
    float k1f = bf2f(k1[jj]), k2f = bf2f(k2[jj]);
    oq1[jj] = f2bf((q1f * cs - q2f * sn) * QSCALE);
    oq2[jj] = f2bf((q2f * cs + q1f * sn) * QSCALE);
    ok1[jj] = f2bf(k1f * cs - k2f * sn);
    ok2[jj] = f2bf(k2f * cs + k1f * sn);
    T[row * 67 + j0 + jj] = v1[jj];
    T[row * 67 + 32 + j0 + jj] = v2[jj];
  }
  size_t o = ((size_t)bh * SQ + gs) * 64;
  *(u16x8*)(qp + o + j0) = oq1;
  *(u16x8*)(qp + o + 32 + j0) = oq2;
  *(u16x8*)(kp + o + j0) = ok1;
  *(u16x8*)(kp + o + 32 + j0) = ok2;
  __syncthreads();
  // transposed V out: [bh][hd][s]
  int hd = tid >> 2;
#pragma unroll
  for (int c2 = 0; c2 < 2; ++c2) {
    int sb = q4 * 16 + c2 * 8;
    u16x8 ov;
#pragma unroll
    for (int ii = 0; ii < 8; ++ii) ov[ii] = T[(sb + ii) * 67 + hd];
    *(u16x8*)(vpT + ((size_t)bh * 64 + hd) * SQ + s0 + sb) = ov;
  }
}

// ---------------- causal flash attention: QB=64 (4 waves x 16 rows), KV tile 64 ----------------
__global__ __launch_bounds__(256) void k_flash(const unsigned short* __restrict__ qp,
                                               const unsigned short* __restrict__ kp,
                                               const unsigned short* __restrict__ vpT,
                                               unsigned short* __restrict__ ctx) {
  __shared__ __align__(16) unsigned short Ks[2][64 * 64];
  __shared__ __align__(16) unsigned short Vs[2][64 * 64];
  __shared__ __align__(16) unsigned short Ps[4][16 * 64];
  int qb = 31 - (int)blockIdx.x; // heavy blocks first
  int bh = blockIdx.y, b = bh >> 4, hh = bh & 15;
  int tid = threadIdx.x, lane = tid & 63, w = tid >> 6;
  const int lr = lane & 15, lg = lane >> 4;
  const int key = lr & 7;
  size_t hoff = (size_t)bh * SQ * 64;
  const unsigned short* Q = qp + hoff;
  const unsigned short* Kg = kp + hoff;
  const unsigned short* Vh = vpT + hoff; // [64 hd][2048 s]
  int qr0 = qb * 64 + w * 16;
  bf16x8 aq0 = *(const bf16x8*)(Q + (size_t)(qr0 + lr) * 64 + lg * 8);
  bf16x8 aq1 = *(const bf16x8*)(Q + (size_t)(qr0 + lr) * 64 + 32 + lg * 8);
  f32x4 accO[4] = {};
  float mrow[4] = {-1e30f, -1e30f, -1e30f, -1e30f};
  float lrow[4] = {0.f, 0.f, 0.f, 0.f};
  int nt = qb + 1;

#define STAGE(d, t)                                                              \
  {                                                                              \
    int kv0s = (t) * 64;                                                         \
    _Pragma("unroll") for (int i = 0; i < 2; ++i) {                              \
      int flat = i * 256 + tid;                                                  \
      int srow = flat >> 3;                                                      \
      int ch = (flat & 7) ^ (srow & 7);                                          \
      GLD16(Kg + (size_t)(kv0s + srow) * 64 + ch * 8, &Ks[d][(i * 256 + w * 64) * 8]); \
      GLD16(Vh + (size_t)srow * SQ + kv0s + ch * 8, &Vs[d][(i * 256 + w * 64) * 8]);   \
    }                                                                            \
  }

  STAGE(0, 0);
  __syncthreads();
  for (int t = 0; t < nt; ++t) {
    int kv0 = t * 64;
    if (t + 1 < nt) STAGE((t + 1) & 1, t + 1); // async prefetch; drained by loop-end barrier
    const unsigned short* Kc = Ks[t & 1];
    const unsigned short* Vc = Vs[t & 1];
    f32x4 sacc[4] = {};
#pragma unroll
    for (int nh = 0; nh < 4; ++nh) {
      const unsigned short* kr = Kc + (nh * 16 + lr) * 64;
      bf16x8 b0 = *(const bf16x8*)(kr + (lg ^ key) * 8);
      bf16x8 b1 = *(const bf16x8*)(kr + ((lg + 4) ^ key) * 8);
      sacc[nh] = __builtin_amdgcn_mfma_f32_16x16x32_bf16(aq0, b0, sacc[nh], 0, 0, 0);
      sacc[nh] = __builtin_amdgcn_mfma_f32_16x16x32_bf16(aq1, b1, sacc[nh], 0, 0, 0);
    }
    bool diag = (t == qb);
    float scl[4];
#pragma unroll
    for (int i = 0; i < 4; ++i) {
      float s0 = sacc[0][i], s1 = sacc[1][i], s2 = sacc[2][i], s3 = sacc[3][i];
      if (diag) {
        int gr = qr0 + lg * 4 + i;
        int c = kv0 + lr;
        if (c > gr) s0 = -1e30f;
        if (c + 16 > gr) s1 = -1e30f;
        if (c + 32 > gr) s2 = -1e30f;
        if (c + 48 > gr) s3 = -1e30f;
      }
      float mt = fmaxf(fmaxf(s0, s1), fmaxf(s2, s3));
      mt = fmaxf(mt, __shfl_xor(mt, 1));
      mt = fmaxf(mt, __shfl_xor(mt, 2));
      mt = fmaxf(mt, __shfl_xor(mt, 4));
      mt = fmaxf(mt, __shfl_xor(mt, 8));
      float mnew = fmaxf(mrow[i], mt);
      scl[i] = exp2f(mrow[i] - mnew);
      mrow[i] = mnew;
      float p0 = exp2f(s0 - mnew), p1 = exp2f(s1 - mnew);
      float p2 = exp2f(s2 - mnew), p3 = exp2f(s3 - mnew);
      lrow[i] = lrow[i] * scl[i] + (p0 + p1 + p2 + p3); // per-lane partial; reduced once at end
      int prow = lg * 4 + i;
      unsigned short* Pr = &Ps[w][prow * 64];
      int pk = prow & 7;
      int sub = lr >> 3, off = lr & 7;
      Pr[((0 + sub) ^ pk) * 8 + off] = f2bf(p0);
      Pr[((2 + sub) ^ pk) * 8 + off] = f2bf(p1);
      Pr[((4 + sub) ^ pk) * 8 + off] = f2bf(p2);
      Pr[((6 + sub) ^ pk) * 8 + off] = f2bf(p3);
    }
#pragma unroll
    for (int n2 = 0; n2 < 4; ++n2)
#pragma unroll
      for (int i = 0; i < 4; ++i) accO[n2][i] *= scl[i];
    bf16x8 ap0 = *(const bf16x8*)(&Ps[w][lr * 64] + (lg ^ key) * 8);
    bf16x8 ap1 = *(const bf16x8*)(&Ps[w][lr * 64] + ((lg + 4) ^ key) * 8);
#pragma unroll
    for (int n2 = 0; n2 < 4; ++n2) {
      const unsigned short* vr = Vc + (n2 * 16 + lr) * 64;
      bf16x8 bv0 = *(const bf16x8*)(vr + (lg ^ key) * 8);
      bf16x8 bv1 = *(const bf16x8*)(vr + ((lg + 4) ^ key) * 8);
      accO[n2] = __builtin_amdgcn_mfma_f32_16x16x32_bf16(ap0, bv0, accO[n2], 0, 0, 0);
      accO[n2] = __builtin_amdgcn_mfma_f32_16x16x32_bf16(ap1, bv1, accO[n2], 0, 0, 0);
    }
    __syncthreads(); // drains prefetch vmcnt + protects dbuf
  }
#pragma unroll
  for (int i = 0; i < 4; ++i) {
    float l = lrow[i];
    l += __shfl_xor(l, 1);
    l += __shfl_xor(l, 2);
    l += __shfl_xor(l, 4);
    l += __shfl_xor(l, 8);
    lrow[i] = 1.0f / l;
  }
#pragma unroll
  for (int n2 = 0; n2 < 4; ++n2)
#pragma unroll
    for (int i = 0; i < 4; ++i) {
      int gs = qr0 + lg * 4 + i;
      ctx[((size_t)b * SQ + gs) * DQ + hh * 64 + n2 * 16 + lr] = f2bf(accO[n2][i] * lrow[i]);
    }
#undef STAGE
}

// ---------------- launch ----------------
extern "C" void kernel_launch(void* const* d_in, const int* in_sizes, int n_in,
                              void* d_out, int out_size, void* d_ws, size_t ws_size,
                              hipStream_t stream) {
  (void)in_sizes; (void)n_in; (void)out_size; (void)ws_size;
  const float* x   = (const float*)d_in[0];
  const int*   pos = (const int*)d_in[1];
  // d_in[2] = mask (always causal tril; handled analytically)
  const float* wq  = (const float*)d_in[3];
  const float* wk  = (const float*)d_in[4];
  const float* wv  = (const float*)d_in[5];
  const float* wo  = (const float*)d_in[6];
  const float* wg  = (const float*)d_in[7];
  const float* wu  = (const float*)d_in[8];
  const float* wd  = (const float*)d_in[9];
  const float* n1  = (const float*)d_in[10];
  const float* n2v = (const float*)d_in[11];
  char* ws = (char*)d_ws;
  const size_t MB = 1024ull * 1024ull;
  // workspace map (192 MB total, with lifetime-based aliasing):
  unsigned short* qkvT  = (unsigned short*)(ws);            // [3072][1024] bf16, 6MB
  unsigned short* woT   = (unsigned short*)(ws + 6 * MB);   // [1024][1024] 2MB
  unsigned short* gateT = (unsigned short*)(ws + 8 * MB);   // [4096][1024] 8MB
  unsigned short* upT   = (unsigned short*)(ws + 16 * MB);  // 8MB
  unsigned short* downT = (unsigned short*)(ws + 24 * MB);  // [1024][4096] 8MB
  unsigned short* qkv   = (unsigned short*)(ws + 32 * MB);  // [8192][3072] 48MB (dead after rope)
  unsigned short* act   = qkv;                              // [8192][4096] 64MB (qkv+qp dead by then)
  unsigned short* qpb   = (unsigned short*)(ws + 80 * MB);  // [64][2048][64] 16MB
  unsigned short* kpb   = (unsigned short*)(ws + 96 * MB);  // 16MB
  unsigned short* vpT   = (unsigned short*)(ws + 112 * MB); // [64][64][2048] 16MB
  unsigned short* hbuf  = (unsigned short*)(ws + 128 * MB); // [8192][1024] 16MB (reused as ctx)
  unsigned short* ctx   = hbuf;
  float*          x2    = (float*)(ws + 144 * MB);          // [8192][1024] f32 32MB
  unsigned short* h2    = (unsigned short*)(ws + 176 * MB); // 16MB
  float*          out   = (float*)d_out;

  dim3 b256(256);
  // weights -> bf16 transposed (B^T form)
  k_transpose_bf16<<<dim3(32, 32), b256, 0, stream>>>(wq, qkvT, 1024, 1024);
  k_transpose_bf16<<<dim3(32, 32), b256, 0, stream>>>(wk, qkvT + 1024 * 1024, 1024, 1024);
  k_transpose_bf16<<<dim3(32, 32), b256, 0, stream>>>(wv, qkvT + 2 * 1024 * 1024, 1024, 1024);
  k_transpose_bf16<<<dim3(32, 32), b256, 0, stream>>>(wo, woT, 1024, 1024);
  k_transpose_bf16<<<dim3(128, 32), b256, 0, stream>>>(wg, gateT, 1024, 4096);
  k_transpose_bf16<<<dim3(128, 32), b256, 0, stream>>>(wu, upT, 1024, 4096);
  k_transpose_bf16<<<dim3(32, 128), b256, 0, stream>>>(wd, downT, 4096, 1024);
  // attention block
  k_rmsnorm<<<MROWS, b256, 0, stream>>>(x, n1, hbuf);
  k_gemm256<0><<<dim3(384), dim3(512), 0, stream>>>(hbuf, qkvT, qkv, MROWS, 3072, 1024);
  k_rope<<<dim3(32, 64), b256, 0, stream>>>(qkv, pos, qpb, kpb, vpT);
  k_flash<<<dim3(32, 64), b256, 0, stream>>>(qpb, kpb, vpT, ctx);
  k_gemm_bt<1><<<dim3(8, 64), b256, 0, stream>>>(ctx, woT, x2, x, MROWS, 1024, 1024);
  // FFN block
  k_rmsnorm<<<MROWS, b256, 0, stream>>>(x2, n2v, h2);
  k_gemm256<0><<<dim3(512), dim3(512), 0, stream>>>(h2, upT, act, MROWS, 4096, 1024);
  k_gemm256<2><<<dim3(512), dim3(512), 0, stream>>>(h2, gateT, act, MROWS, 4096, 1024);
  k_gemm_bt<1><<<dim3(8, 64), b256, 0, stream>>>(act, downT, out, x2, MROWS, 1024, 4096);
}

// Round 7
// 814.390 us; speedup vs baseline: 1.2308x; 1.0197x over previous
//
#include <hip/hip_runtime.h>
#include <cstdint>
#include <cstddef>

// ---------------- constants ----------------
#define BQ 4
#define SQ 2048
#define DQ 1024
#define HQ 16
#define HDQ 64
#define FQ 4096
#define MROWS (BQ * SQ) // 8192

typedef __attribute__((ext_vector_type(8))) __bf16 bf16x8;
typedef __attribute__((ext_vector_type(8))) unsigned short u16x8;
typedef __attribute__((ext_vector_type(4))) float f32x4;

__device__ __forceinline__ unsigned short f2bf(float f) {
  unsigned int u = __builtin_bit_cast(unsigned int, f);
  u = (u + 0x7FFFu + ((u >> 16) & 1u)) >> 16;
  return (unsigned short)u;
}
__device__ __forceinline__ unsigned short f2bf_trunc(float f) {
  return (unsigned short)(__builtin_bit_cast(unsigned int, f) >> 16);
}
__device__ __forceinline__ float bf2f(unsigned short h) {
  unsigned int u = ((unsigned int)h) << 16;
  return __builtin_bit_cast(float, u);
}
// gelu(v) = v * sigmoid(2*0.7978845608*(v+0.044715 v^3)); sigmoid via exp2+rcp
__device__ __forceinline__ float gelu_f(float v) {
  float t = v + 0.044715f * v * v * v;
  float e = exp2f(-2.3022082299f * t);
  return v * __builtin_amdgcn_rcpf(1.0f + e);
}

typedef const unsigned int __attribute__((address_space(1))) *as1_cu32;
typedef unsigned int __attribute__((address_space(3))) *as3_u32;
// async global->LDS, 16B per lane; LDS dest is wave-uniform base + lane*16
#define GLD16(g, l) __builtin_amdgcn_global_load_lds((as1_cu32)(const void*)(g), (as3_u32)(void*)(l), 16, 0, 0)

// ---------------- weight transpose+convert: src[R][C] f32 -> dst[C][R] bf16 ----------------
__global__ __launch_bounds__(256) void k_transpose_bf16(const float* __restrict__ src,
                                                        unsigned short* __restrict__ dst,
                                                        int R, int C) {
  __shared__ float tile[32][33];
  int tx = threadIdx.x & 31, ty = threadIdx.x >> 5; // ty 0..7
  int c0 = blockIdx.x * 32, r0 = blockIdx.y * 32;
#pragma unroll
  for (int i = 0; i < 32; i += 8)
    tile[ty + i][tx] = src[(size_t)(r0 + ty + i) * C + (c0 + tx)];
  __syncthreads();
#pragma unroll
  for (int i = 0; i < 32; i += 8)
    dst[(size_t)(c0 + ty + i) * R + (r0 + tx)] = f2bf(tile[tx][ty + i]);
}

// ---------------- RMSNorm: f32 in -> bf16 out, one block per row (D=1024) ----------------
__global__ __launch_bounds__(256) void k_rmsnorm(const float* __restrict__ x,
                                                 const float* __restrict__ g,
                                                 unsigned short* __restrict__ out) {
  int row = blockIdx.x, tid = threadIdx.x;
  const float4 v = ((const float4*)(x + (size_t)row * DQ))[tid];
  float ss = v.x * v.x + v.y * v.y + v.z * v.z + v.w * v.w;
#pragma unroll
  for (int d = 32; d >= 1; d >>= 1) ss += __shfl_xor(ss, d);
  __shared__ float ws4[4];
  if ((tid & 63) == 0) ws4[tid >> 6] = ss;
  __syncthreads();
  float tot = ws4[0] + ws4[1] + ws4[2] + ws4[3];
  float r = rsqrtf(tot * (1.0f / DQ) + 1e-6f);
  const float4 gv = ((const float4*)g)[tid];
  ushort4 o;
  o.x = f2bf(v.x * r * gv.x);
  o.y = f2bf(v.y * r * gv.y);
  o.z = f2bf(v.z * r * gv.z);
  o.w = f2bf(v.w * r * gv.w);
  ((ushort4*)(out + (size_t)row * DQ))[tid] = o;
}

// ---------------- 128x128 GEMM (m97 structure): kept for N=1024 outputs ----------------
// MODE 0: C bf16.  MODE 1: C f32 = acc + Res.  MODE 2: C bf16 = gelu(acc) * bf2f(C_prev)
template <int MODE>
__global__ __launch_bounds__(256) void k_gemm_bt(const unsigned short* __restrict__ A,
                                                 const unsigned short* __restrict__ Bt,
                                                 void* __restrict__ Cp,
                                                 const float* __restrict__ Res,
                                                 int M, int N, int K) {
  __shared__ __align__(16) unsigned short As[128 * 32];
  __shared__ __align__(16) unsigned short Bs[128 * 32];
  const int tid = threadIdx.x;
  const int lane = tid & 63, w = tid >> 6;
  const int m0 = blockIdx.y * 128, n0 = blockIdx.x * 128;
  const int wm = (w >> 1) * 64, wn = (w & 1) * 64;
  const int lr = lane & 15, lg = lane >> 4;
  f32x4 acc[4][4] = {};
  for (int k0 = 0; k0 < K; k0 += 32) {
#pragma unroll
    for (int i = 0; i < 2; ++i) {
      int flat = i * 256 + tid;
      int row = flat >> 2, ch = flat & 3;
      GLD16(A + (size_t)(m0 + row) * K + k0 + ch * 8, As + (size_t)(i * 256 + w * 64) * 8);
      GLD16(Bt + (size_t)(n0 + row) * K + k0 + ch * 8, Bs + (size_t)(i * 256 + w * 64) * 8);
    }
    __syncthreads();
    bf16x8 af[4], bfr[4];
#pragma unroll
    for (int mi = 0; mi < 4; ++mi)
      af[mi] = *(const bf16x8*)(As + (wm + mi * 16 + lr) * 32 + lg * 8);
#pragma unroll
    for (int ni = 0; ni < 4; ++ni)
      bfr[ni] = *(const bf16x8*)(Bs + (wn + ni * 16 + lr) * 32 + lg * 8);
#pragma unroll
    for (int mi = 0; mi < 4; ++mi)
#pragma unroll
      for (int ni = 0; ni < 4; ++ni)
        acc[mi][ni] = __builtin_amdgcn_mfma_f32_16x16x32_bf16(af[mi], bfr[ni], acc[mi][ni], 0, 0, 0);
    __syncthreads();
  }
#pragma unroll
  for (int mi = 0; mi < 4; ++mi) {
#pragma unroll
    for (int r = 0; r < 4; ++r) {
      int gr = m0 + wm + mi * 16 + lg * 4 + r;
#pragma unroll
      for (int ni = 0; ni < 4; ++ni) {
        int gc = n0 + wn + ni * 16 + lr;
        size_t idx = (size_t)gr * N + gc;
        float v = acc[mi][ni][r];
        if (MODE == 0) {
          ((unsigned short*)Cp)[idx] = f2bf(v);
        } else if (MODE == 1) {
          ((float*)Cp)[idx] = v + Res[idx];
        } else {
          float u = bf2f(((unsigned short*)Cp)[idx]);
          ((unsigned short*)Cp)[idx] = f2bf(gelu_f(v) * u);
        }
      }
    }
  }
}

// ---------------- 256x256 8-phase GEMM (T1+T2+T3+T4+T5), BK=64, 8 waves ----------------
template <int MODE>
__global__ __launch_bounds__(512, 2) void k_gemm256(const unsigned short* __restrict__ A,
                                                    const unsigned short* __restrict__ Bt,
                                                    void* __restrict__ Cp,
                                                    int M, int N, int K) {
  __shared__ __align__(16) unsigned short Ab[2][2][128 * 64];
  __shared__ __align__(16) unsigned short Bb[2][2][128 * 64];
  const int tid = threadIdx.x, lane = tid & 63, w = tid >> 6;
  const int nwg = (int)gridDim.x;
  const int nx = N >> 8;
  const int cpx = nwg >> 3; // nwg % 8 == 0 for all our launches
  const int bid = (int)blockIdx.x;
  const int swz = (bid & 7) * cpx + (bid >> 3); // bijective XCD swizzle
  const int bx = swz % nx, by = swz / nx;
  const int m0 = by * 256, n0 = bx * 256;
  const int wr = (w >> 2) * 128, wc = (w & 3) * 64;
  const int lr = lane & 15, lg = lane >> 4;
  const int NT = K >> 6;
  const int r0 = tid >> 3;                    // rows r0 and r0+64
  const int c0sw = (tid & 7) ^ (r0 & 7);      // same swizzled chunk for both rows
  f32x4 acc[8][4] = {};

#define BAR() asm volatile("s_barrier" ::: "memory")

#define STG(isB, hh_, t_)                                                         \
  do {                                                                            \
    int tpar = (t_) & 1;                                                          \
    int t2 = (t_) > NT - 1 ? NT - 1 : (t_);                                       \
    const unsigned short* gb = (isB) ? Bt : A;                                    \
    int rb = ((isB) ? n0 : m0) + (hh_) * 128;                                     \
    unsigned short* lb =                                                          \
        ((isB) ? &Bb[tpar][hh_][0] : &Ab[tpar][hh_][0]) + (size_t)(w * 64) * 8;   \
    const unsigned short* g0 = gb + (size_t)(rb + r0) * K + t2 * 64 + c0sw * 8;   \
    GLD16(g0, lb);                                                                \
    GLD16(g0 + (size_t)64 * K, lb + 512 * 8);                                     \
  } while (0)

#define RD_A(dst, MH, par)                                                        \
  _Pragma("unroll") for (int mi2 = 0; mi2 < 4; ++mi2) {                           \
    int rr = (wr + ((MH)*4 + mi2) * 16 + lr) & 127;                               \
    int hh = wr >> 7;                                                             \
    _Pragma("unroll") for (int ks = 0; ks < 2; ++ks)                              \
        dst[mi2][ks] =                                                            \
        *(const bf16x8*)&Ab[par][hh][rr * 64 + (((ks * 4 + lg) ^ (rr & 7)) * 8)]; \
  }

#define RD_B(dst, NH, par)                                                        \
  _Pragma("unroll") for (int ni2 = 0; ni2 < 2; ++ni2) {                           \
    int c256 = wc + ((NH)*2 + ni2) * 16 + lr;                                     \
    int hh = c256 >> 7, rr = c256 & 127;                                          \
    _Pragma("unroll") for (int ks = 0; ks < 2; ++ks)                              \
        dst[ni2][ks] =                                                            \
        *(const bf16x8*)&Bb[par][hh][rr * 64 + (((ks * 4 + lg) ^ (rr & 7)) * 8)]; \
  }

#define MM(MH, NH, aqv, bqv)                                                      \
  _Pragma("unroll") for (int mi2 = 0; mi2 < 4; ++mi2)                             \
  _Pragma("unroll") for (int ni2 = 0; ni2 < 2; ++ni2)                             \
  _Pragma("unroll") for (int ks = 0; ks < 2; ++ks)                                \
      acc[(MH)*4 + mi2][(NH)*2 + ni2] = __builtin_amdgcn_mfma_f32_16x16x32_bf16(  \
          aqv[mi2][ks], bqv[ni2][ks], acc[(MH)*4 + mi2][(NH)*2 + ni2], 0, 0, 0);

  STG(0, 0, 0);
  STG(0, 1, 0);
  STG(1, 0, 0);
  STG(1, 1, 0);
  STG(1, 0, 1);
  STG(1, 1, 1);
  asm volatile("s_waitcnt vmcnt(4)" ::: "memory");
  BAR();

  for (int kt = 0; kt < NT; ++kt) {
    const int p = kt & 1;
    bf16x8 aq[4][2], bq0[2][2], bq1[2][2];
    RD_A(aq, 0, p);
    RD_B(bq0, 0, p);
    STG(0, 0, kt + 1);
    BAR();
    __builtin_amdgcn_s_setprio(1);
    MM(0, 0, aq, bq0);
    __builtin_amdgcn_s_setprio(0);
    BAR();
    RD_B(bq1, 1, p);
    STG(0, 1, kt + 1);
    BAR();
    __builtin_amdgcn_s_setprio(1);
    MM(0, 1, aq, bq1);
    __builtin_amdgcn_s_setprio(0);
    BAR();
    RD_A(aq, 1, p);
    STG(1, 0, kt + 2);
    BAR();
    __builtin_amdgcn_s_setprio(1);
    MM(1, 1, aq, bq1);
    __builtin_amdgcn_s_setprio(0);
    BAR();
    STG(1, 1, kt + 2);
    asm volatile("s_waitcnt vmcnt(4)" ::: "memory");
    BAR();
    __builtin_amdgcn_s_setprio(1);
    MM(1, 0, aq, bq0);
    __builtin_amdgcn_s_setprio(0);
    BAR();
  }
  asm volatile("s_waitcnt vmcnt(0)" ::: "memory");
#pragma unroll
  for (int mi = 0; mi < 8; ++mi) {
#pragma unroll
    for (int r = 0; r < 4; ++r) {
      int gr = m0 + wr + mi * 16 + lg * 4 + r;
#pragma unroll
      for (int ni = 0; ni < 4; ++ni) {
        int gc = n0 + wc + ni * 16 + lr;
        size_t idx = (size_t)gr * N + gc;
        float v = acc[mi][ni][r];
        if (MODE == 0) {
          ((unsigned short*)Cp)[idx] = f2bf(v);
        } else {
          float u = bf2f(((unsigned short*)Cp)[idx]);
          ((unsigned short*)Cp)[idx] = f2bf(gelu_f(v) * u);
        }
      }
    }
  }
#undef BAR
#undef STG
#undef RD_A
#undef RD_B
#undef MM
}

// ---------------- RoPE: qkv[b,s,3*D] -> qp/kp [bh][s][64], V -> vpT [bh][hd][s] ----------------
__global__ __launch_bounds__(256) void k_rope(const unsigned short* __restrict__ qkv,
                                              const int* __restrict__ pos,
                                              unsigned short* __restrict__ qp,
                                              unsigned short* __restrict__ kp,
                                              unsigned short* __restrict__ vpT) {
  __shared__ unsigned short T[64 * 67]; // [s_local][hd], stride 67 to spread banks
  const float NEG_L2TS = -0.4152410118609203f; // -log2(10000)/32
  const float QSCALE = 0.125f * 1.4426950408889634f;
  int bh = blockIdx.y, b = bh >> 4, hh = bh & 15;
  int s0 = blockIdx.x * 64;
  int tid = threadIdx.x;
  int row = tid >> 2, q4 = tid & 3, j0 = q4 * 8;
  int gs = s0 + row;
  const unsigned short* base = qkv + ((size_t)(b * SQ + gs)) * 3072 + hh * 64;
  u16x8 q1 = *(const u16x8*)(base + j0);
  u16x8 q2 = *(const u16x8*)(base + 32 + j0);
  u16x8 k1 = *(const u16x8*)(base + 1024 + j0);
  u16x8 k2 = *(const u16x8*)(base + 1024 + 32 + j0);
  u16x8 v1 = *(const u16x8*)(base + 2048 + j0);
  u16x8 v2 = *(const u16x8*)(base + 2048 + 32 + j0);
  float fp = (float)pos[b * SQ + gs];
  u16x8 oq1, oq2, ok1, ok2;
#pragma unroll
  for (int jj = 0; jj < 8; ++jj) {
    float ang = fp * exp2f((float)(j0 + jj) * NEG_L2TS);
    float sn, cs;
    __sincosf(ang, &sn, &cs);
    float q1f = bf2f(q1[jj]), q2f = bf2f(q2[jj]);
    float k1f = bf2f(k1[jj]), k2f = bf2f(k2[jj]);
    oq1[jj] = f2bf((q1f * cs - q2f * sn) * QSCALE);
    oq2[jj] = f2bf((q2f * cs + q1f * sn) * QSCALE);
    ok1[jj] = f2bf(k1f * cs - k2f * sn);
    ok2[jj] = f2bf(k2f * cs + k1f * sn);
    T[row * 67 + j0 + jj] = v1[jj];
    T[row * 67 + 32 + j0 + jj] = v2[jj];
  }
  size_t o = ((size_t)bh * SQ + gs) * 64;
  *(u16x8*)(qp + o + j0) = oq1;
  *(u16x8*)(qp + o + 32 + j0) = oq2;
  *(u16x8*)(kp + o + j0) = ok1;
  *(u16x8*)(kp + o + 32 + j0) = ok2;
  __syncthreads();
  // transposed V out: [bh][hd][s]
  int hd = tid >> 2;
#pragma unroll
  for (int c2 = 0; c2 < 2; ++c2) {
    int sb = q4 * 16 + c2 * 8;
    u16x8 ov;
#pragma unroll
    for (int ii = 0; ii < 8; ++ii) ov[ii] = T[(sb + ii) * 67 + hd];
    *(u16x8*)(vpT + ((size_t)bh * 64 + hd) * SQ + s0 + sb) = ov;
  }
}

// ---------------- causal flash attention: QB=128 (4 waves x 32 rows), KV tile 64 ----------------
// K tile [kv][64], V^T tile [hd][kv] staged via swizzled-source global_load_lds.
__global__ __launch_bounds__(256, 3) void k_flash(const unsigned short* __restrict__ qp,
                                                  const unsigned short* __restrict__ kp,
                                                  const unsigned short* __restrict__ vpT,
                                                  unsigned short* __restrict__ ctx) {
  __shared__ __align__(16) unsigned short Ks[2][64 * 64];
  __shared__ __align__(16) unsigned short Vs[2][64 * 64];
  __shared__ __align__(16) unsigned short Ps[4][32 * 64];
  int qb = 15 - (int)blockIdx.x; // heavy blocks first
  int bh = blockIdx.y, b = bh >> 4, hh = bh & 15;
  int tid = threadIdx.x, lane = tid & 63, w = tid >> 6;
  const int lr = lane & 15, lg = lane >> 4;
  const int key = lr & 7;
  size_t hoff = (size_t)bh * SQ * 64;
  const unsigned short* Q = qp + hoff;
  const unsigned short* Kg = kp + hoff;
  const unsigned short* Vh = vpT + hoff; // [64 hd][2048 s]
  int qr0 = qb * 128 + w * 32; // wave owns rows qr0..qr0+31
  bf16x8 aq[2][2];
#pragma unroll
  for (int mi = 0; mi < 2; ++mi) {
    aq[mi][0] = *(const bf16x8*)(Q + (size_t)(qr0 + mi * 16 + lr) * 64 + lg * 8);
    aq[mi][1] = *(const bf16x8*)(Q + (size_t)(qr0 + mi * 16 + lr) * 64 + 32 + lg * 8);
  }
  f32x4 accO[2][4] = {};
  float mrow[2][4], lrow[2][4];
#pragma unroll
  for (int mi = 0; mi < 2; ++mi)
#pragma unroll
    for (int i = 0; i < 4; ++i) { mrow[mi][i] = -1e30f; lrow[mi][i] = 0.f; }
  int nt = qb * 2 + 2;

#define STAGE(d, t)                                                              \
  {                                                                              \
    int kv0s = (t) * 64;                                                         \
    _Pragma("unroll") for (int i = 0; i < 2; ++i) {                              \
      int flat = i * 256 + tid;                                                  \
      int srow = flat >> 3;                                                      \
      int ch = (flat & 7) ^ (srow & 7);                                          \
      GLD16(Kg + (size_t)(kv0s + srow) * 64 + ch * 8, &Ks[d][(i * 256 + w * 64) * 8]); \
      GLD16(Vh + (size_t)srow * SQ + kv0s + ch * 8, &Vs[d][(i * 256 + w * 64) * 8]);   \
    }                                                                            \
  }

  STAGE(0, 0);
  __syncthreads();
  for (int t = 0; t < nt; ++t) {
    int kv0 = t * 64;
    if (t + 1 < nt) STAGE((t + 1) & 1, t + 1); // async prefetch; drained by loop-end barrier
    const unsigned short* Kc = Ks[t & 1];
    const unsigned short* Vc = Vs[t & 1];
    bool active = (kv0 <= qr0 + 31); // wave-uniform causal cull
    if (active) {
      f32x4 sacc[2][4] = {};
#pragma unroll
      for (int nh = 0; nh < 4; ++nh) {
        const unsigned short* kr = Kc + (nh * 16 + lr) * 64;
        bf16x8 b0 = *(const bf16x8*)(kr + (lg ^ key) * 8);
        bf16x8 b1 = *(const bf16x8*)(kr + ((lg + 4) ^ key) * 8);
#pragma unroll
        for (int mi = 0; mi < 2; ++mi) {
          sacc[mi][nh] = __builtin_amdgcn_mfma_f32_16x16x32_bf16(aq[mi][0], b0, sacc[mi][nh], 0, 0, 0);
          sacc[mi][nh] = __builtin_amdgcn_mfma_f32_16x16x32_bf16(aq[mi][1], b1, sacc[mi][nh], 0, 0, 0);
        }
      }
      bool diag = (kv0 + 63 > qr0); // tile overlaps the diagonal for this wave
      float scl[2][4];
#pragma unroll
      for (int mi = 0; mi < 2; ++mi) {
#pragma unroll
        for (int i = 0; i < 4; ++i) {
          float s0 = sacc[mi][0][i], s1 = sacc[mi][1][i], s2 = sacc[mi][2][i], s3 = sacc[mi][3][i];
          if (diag) {
            int gr = qr0 + mi * 16 + lg * 4 + i;
            int c = kv0 + lr;
            if (c > gr) s0 = -1e30f;
            if (c + 16 > gr) s1 = -1e30f;
            if (c + 32 > gr) s2 = -1e30f;
            if (c + 48 > gr) s3 = -1e30f;
          }
          float mt = fmaxf(fmaxf(s0, s1), fmaxf(s2, s3));
          mt = fmaxf(mt, __shfl_xor(mt, 1));
          mt = fmaxf(mt, __shfl_xor(mt, 2));
          mt = fmaxf(mt, __shfl_xor(mt, 4));
          mt = fmaxf(mt, __shfl_xor(mt, 8));
          float mnew = fmaxf(mrow[mi][i], mt);
          scl[mi][i] = exp2f(mrow[mi][i] - mnew);
          mrow[mi][i] = mnew;
          float p0 = exp2f(s0 - mnew), p1 = exp2f(s1 - mnew);
          float p2 = exp2f(s2 - mnew), p3 = exp2f(s3 - mnew);
          lrow[mi][i] = lrow[mi][i] * scl[mi][i] + (p0 + p1 + p2 + p3);
          int prow = mi * 16 + lg * 4 + i;
          unsigned short* Pr = &Ps[w][prow * 64];
          int pk = prow & 7;
          int sub = lr >> 3, off = lr & 7;
          Pr[((0 + sub) ^ pk) * 8 + off] = f2bf_trunc(p0);
          Pr[((2 + sub) ^ pk) * 8 + off] = f2bf_trunc(p1);
          Pr[((4 + sub) ^ pk) * 8 + off] = f2bf_trunc(p2);
          Pr[((6 + sub) ^ pk) * 8 + off] = f2bf_trunc(p3);
        }
#pragma unroll
        for (int n2 = 0; n2 < 4; ++n2)
#pragma unroll
          for (int i = 0; i < 4; ++i) accO[mi][n2][i] *= scl[mi][i];
      }
      bf16x8 ap[2][2];
#pragma unroll
      for (int mi = 0; mi < 2; ++mi) {
        const unsigned short* pr = &Ps[w][(mi * 16 + lr) * 64];
        ap[mi][0] = *(const bf16x8*)(pr + (lg ^ key) * 8);
        ap[mi][1] = *(const bf16x8*)(pr + ((lg + 4) ^ key) * 8);
      }
#pragma unroll
      for (int n2 = 0; n2 < 4; ++n2) {
        const unsigned short* vr = Vc + (n2 * 16 + lr) * 64;
        bf16x8 bv0 = *(const bf16x8*)(vr + (lg ^ key) * 8);
        bf16x8 bv1 = *(const bf16x8*)(vr + ((lg + 4) ^ key) * 8);
#pragma unroll
        for (int mi = 0; mi < 2; ++mi) {
          accO[mi][n2] = __builtin_amdgcn_mfma_f32_16x16x32_bf16(ap[mi][0], bv0, accO[mi][n2], 0, 0, 0);
          accO[mi][n2] = __builtin_amdgcn_mfma_f32_16x16x32_bf16(ap[mi][1], bv1, accO[mi][n2], 0, 0, 0);
        }
      }
    }
    __syncthreads(); // drains prefetch vmcnt + protects dbuf
  }
#pragma unroll
  for (int mi = 0; mi < 2; ++mi)
#pragma unroll
    for (int i = 0; i < 4; ++i) {
      float l = lrow[mi][i];
      l += __shfl_xor(l, 1);
      l += __shfl_xor(l, 2);
      l += __shfl_xor(l, 4);
      l += __shfl_xor(l, 8);
      lrow[mi][i] = 1.0f / l;
    }
#pragma unroll
  for (int mi = 0; mi < 2; ++mi)
#pragma unroll
    for (int n2 = 0; n2 < 4; ++n2)
#pragma unroll
      for (int i = 0; i < 4; ++i) {
        int gs = qr0 + mi * 16 + lg * 4 + i;
        ctx[((size_t)b * SQ + gs) * DQ + hh * 64 + n2 * 16 + lr] = f2bf(accO[mi][n2][i] * lrow[mi][i]);
      }
#undef STAGE
}

// ---------------- launch ----------------
extern "C" void kernel_launch(void* const* d_in, const int* in_sizes, int n_in,
                              void* d_out, int out_size, void* d_ws, size_t ws_size,
                              hipStream_t stream) {
  (void)in_sizes; (void)n_in; (void)out_size; (void)ws_size;
  const float* x   = (const float*)d_in[0];
  const int*   pos = (const int*)d_in[1];
  // d_in[2] = mask (always causal tril; handled analytically)
  const float* wq  = (const float*)d_in[3];
  const float* wk  = (const float*)d_in[4];
  const float* wv  = (const float*)d_in[5];
  const float* wo  = (const float*)d_in[6];
  const float* wg  = (const float*)d_in[7];
  const float* wu  = (const float*)d_in[8];
  const float* wd  = (const float*)d_in[9];
  const float* n1  = (const float*)d_in[10];
  const float* n2v = (const float*)d_in[11];
  char* ws = (char*)d_ws;
  const size_t MB = 1024ull * 1024ull;
  // workspace map (192 MB total, with lifetime-based aliasing):
  unsigned short* qkvT  = (unsigned short*)(ws);            // [3072][1024] bf16, 6MB
  unsigned short* woT   = (unsigned short*)(ws + 6 * MB);   // [1024][1024] 2MB
  unsigned short* gateT = (unsigned short*)(ws + 8 * MB);   // [4096][1024] 8MB
  unsigned short* upT   = (unsigned short*)(ws + 16 * MB);  // 8MB
  unsigned short* downT = (unsigned short*)(ws + 24 * MB);  // [1024][4096] 8MB
  unsigned short* qkv   = (unsigned short*)(ws + 32 * MB);  // [8192][3072] 48MB (dead after rope)
  unsigned short* act   = qkv;                              // [8192][4096] 64MB (qkv+qp dead by then)
  unsigned short* qpb   = (unsigned short*)(ws + 80 * MB);  // [64][2048][64] 16MB
  unsigned short* kpb   = (unsigned short*)(ws + 96 * MB);  // 16MB
  unsigned short* vpT   = (unsigned short*)(ws + 112 * MB); // [64][64][2048] 16MB
  unsigned short* hbuf  = (unsigned short*)(ws + 128 * MB); // [8192][1024] 16MB (reused as ctx)
  unsigned short* ctx   = hbuf;
  float*          x2    = (float*)(ws + 144 * MB);          // [8192][1024] f32 32MB
  unsigned short* h2    = (unsigned short*)(ws + 176 * MB); // 16MB
  float*          out   = (float*)d_out;

  dim3 b256(256);
  // weights -> bf16 transposed (B^T form)
  k_transpose_bf16<<<dim3(32, 32), b256, 0, stream>>>(wq, qkvT, 1024, 1024);
  k_transpose_bf16<<<dim3(32, 32), b256, 0, stream>>>(wk, qkvT + 1024 * 1024, 1024, 1024);
  k_transpose_bf16<<<dim3(32, 32), b256, 0, stream>>>(wv, qkvT + 2 * 1024 * 1024, 1024, 1024);
  k_transpose_bf16<<<dim3(32, 32), b256, 0, stream>>>(wo, woT, 1024, 1024);
  k_transpose_bf16<<<dim3(128, 32), b256, 0, stream>>>(wg, gateT, 1024, 4096);
  k_transpose_bf16<<<dim3(128, 32), b256, 0, stream>>>(wu, upT, 1024, 4096);
  k_transpose_bf16<<<dim3(32, 128), b256, 0, stream>>>(wd, downT, 4096, 1024);
  // attention block
  k_rmsnorm<<<MROWS, b256, 0, stream>>>(x, n1, hbuf);
  k_gemm256<0><<<dim3(384), dim3(512), 0, stream>>>(hbuf, qkvT, qkv, MROWS, 3072, 1024);
  k_rope<<<dim3(32, 64), b256, 0, stream>>>(qkv, pos, qpb, kpb, vpT);
  k_flash<<<dim3(16, 64), b256, 0, stream>>>(qpb, kpb, vpT, ctx);
  k_gemm_bt<1><<<dim3(8, 64), b256, 0, stream>>>(ctx, woT, x2, x, MROWS, 1024, 1024);
  // FFN block
  k_rmsnorm<<<MROWS, b256, 0, stream>>>(x2, n2v, h2);
  k_gemm256<0><<<dim3(512), dim3(512), 0, stream>>>(h2, upT, act, MROWS, 4096, 1024);
  k_gemm256<2><<<dim3(512), dim3(512), 0, stream>>>(h2, gateT, act, MROWS, 4096, 1024);
  k_gemm_bt<1><<<dim3(8, 64), b256, 0, stream>>>(act, downT, out, x2, MROWS, 1024, 4096);
}